// Round 1
// baseline (3107.647 us; speedup 1.0000x reference)
//
#include <hip/hip_runtime.h>

#define NN 10000
#define NE 160000
#define FIN 1152
#define FOUT 288
#define FOUT_TOTAL 1152

// ---------------- degree / normalization ----------------

__global__ void deg_kernel(const int* __restrict__ ei, int* __restrict__ deg,
                           int* __restrict__ indeg) {
  int e = blockIdx.x * 256 + threadIdx.x;
  if (e < NE) {
    atomicAdd(&deg[ei[e]], 1);        // out-degree by source (row)
    atomicAdd(&indeg[ei[NE + e]], 1); // in-degree by target (col)
  }
}

__global__ void dinv_kernel(const int* __restrict__ deg, float* __restrict__ dinv) {
  int i = blockIdx.x * 256 + threadIdx.x;
  if (i < NN) {
    int d = deg[i];
    dinv[i] = d > 0 ? rsqrtf((float)d) : 0.0f;
  }
}

// single-block exclusive scan of indeg -> rowptr (and cursor copy)
__global__ void scan_kernel(const int* __restrict__ indeg, int* __restrict__ rowptr,
                            int* __restrict__ cursor) {
  __shared__ int s[256];
  __shared__ int carry_s;
  if (threadIdx.x == 0) carry_s = 0;
  __syncthreads();
  for (int base = 0; base < NN; base += 256) {
    int i = base + threadIdx.x;
    int v = (i < NN) ? indeg[i] : 0;
    s[threadIdx.x] = v;
    __syncthreads();
    for (int off = 1; off < 256; off <<= 1) {
      int t = (threadIdx.x >= off) ? s[threadIdx.x - off] : 0;
      __syncthreads();
      s[threadIdx.x] += t;
      __syncthreads();
    }
    int excl = s[threadIdx.x] - v + carry_s;
    if (i < NN) { rowptr[i] = excl; cursor[i] = excl; }
    __syncthreads();
    if (threadIdx.x == 0) carry_s += s[255];
    __syncthreads();
  }
  if (threadIdx.x == 0) rowptr[NN] = carry_s;
}

__global__ void scatter_kernel(const int* __restrict__ ei, const float* __restrict__ dinv,
                               int* __restrict__ cursor, int* __restrict__ srcarr,
                               float* __restrict__ wn) {
  int e = blockIdx.x * 256 + threadIdx.x;
  if (e < NE) {
    int r = ei[e], c = ei[NE + e];
    int pos = atomicAdd(&cursor[c], 1);
    srcarr[pos] = r;
    wn[pos] = -(dinv[r] * dinv[c]);
  }
}

// ---------------- propagation: dst = alpha*prop(H) + beta*Tprev ----------------
// 2 nodes per block, 288 float4 lanes per node (1152 floats).
// In-place safe when dst == Tprev (each element read-then-written by its own thread).
__global__ __launch_bounds__(576) void prop_kernel(
    const float* __restrict__ H, const float* __restrict__ Tprev, float* __restrict__ dst,
    const int* __restrict__ rowptr, const int* __restrict__ srcarr,
    const float* __restrict__ wn, float alpha, float beta) {
  int t = threadIdx.x;
  int sub = (t >= 288) ? 1 : 0;
  int node = blockIdx.x * 2 + sub;
  int f4 = t - sub * 288; // 0..287
  int rs = rowptr[node];
  int re = rowptr[node + 1];
  float4 acc = make_float4(0.f, 0.f, 0.f, 0.f);
  for (int p = rs; p < re; ++p) {
    int r = srcarr[p];
    float w = wn[p];
    float4 h = *(const float4*)(H + (size_t)r * FIN + f4 * 4);
    acc.x += w * h.x; acc.y += w * h.y; acc.z += w * h.z; acc.w += w * h.w;
  }
  size_t o = (size_t)node * FIN + f4 * 4;
  float4 res;
  if (beta != 0.0f) {
    float4 tp = *(const float4*)(Tprev + o);
    res.x = alpha * acc.x + beta * tp.x;
    res.y = alpha * acc.y + beta * tp.y;
    res.z = alpha * acc.z + beta * tp.z;
    res.w = alpha * acc.w + beta * tp.w;
  } else {
    res.x = alpha * acc.x; res.y = alpha * acc.y;
    res.z = alpha * acc.z; res.w = alpha * acc.w;
  }
  *(float4*)(dst + o) = res;
}

// ---------------- bias init ----------------
__global__ void bias_init_kernel(float* __restrict__ out, const float* __restrict__ b0,
                                 const float* __restrict__ b1, const float* __restrict__ b2,
                                 const float* __restrict__ b3) {
  int i = blockIdx.x * 256 + threadIdx.x;
  if (i < NN * FOUT_TOTAL) {
    int j = i % FOUT_TOTAL;
    int c = j / FOUT;
    const float* b = (c == 0) ? b0 : (c == 1) ? b1 : (c == 2) ? b2 : b3;
    out[i] = b[j - c * FOUT];
  }
}

// ---------------- fp32 GEMM accumulate: out[:, c*288:(c+1)*288] += T @ Wc_k ----------------
// BM=64, BN=96 (divides 288), BK=16; 256 threads, 4x6 micro-tile.
#define BM 64
#define BN 96
#define BK 16

__global__ __launch_bounds__(256) void gemm_acc_kernel(
    const float* __restrict__ A, const float* __restrict__ W0, const float* __restrict__ W1,
    const float* __restrict__ W2, const float* __restrict__ W3, float* __restrict__ out,
    int c0) {
  int c = c0 + blockIdx.z;
  const float* __restrict__ W = (c == 0) ? W0 : (c == 1) ? W1 : (c == 2) ? W2 : W3;
  int m0 = blockIdx.x * BM;
  int n0 = blockIdx.y * BN; // within [0,288)
  __shared__ float As[BK][BM];
  __shared__ float Bs[BK][BN];
  int tid = threadIdx.x;
  int ty = tid >> 4; // 0..15
  int tx = tid & 15; // 0..15
  float acc[4][6];
#pragma unroll
  for (int i = 0; i < 4; i++)
#pragma unroll
    for (int j = 0; j < 6; j++) acc[i][j] = 0.0f;

  for (int f0 = 0; f0 < FIN; f0 += BK) {
    // A tile: 64x16, each thread loads float4 along k
    {
      int idx = tid * 4;
      int m = idx >> 4;
      int kk = idx & 15;
      int row = m0 + m;
      float4 v = make_float4(0.f, 0.f, 0.f, 0.f);
      if (row < NN) v = *(const float4*)(A + (size_t)row * FIN + f0 + kk);
      As[kk + 0][m] = v.x; As[kk + 1][m] = v.y; As[kk + 2][m] = v.z; As[kk + 3][m] = v.w;
    }
    // B tile: 16x96, each thread loads 6 consecutive (no row crossing: 96 % 6 == 0)
    {
      int idx = tid * 6;
      int kk = idx / 96;
      int j = idx - kk * 96;
      const float* src = W + (size_t)(f0 + kk) * FOUT + n0 + j;
#pragma unroll
      for (int q = 0; q < 6; q++) Bs[kk][j + q] = src[q];
    }
    __syncthreads();
#pragma unroll
    for (int kk = 0; kk < BK; ++kk) {
      float a[4], b[6];
#pragma unroll
      for (int i = 0; i < 4; i++) a[i] = As[kk][ty * 4 + i];
#pragma unroll
      for (int j = 0; j < 6; j++) b[j] = Bs[kk][tx * 6 + j];
#pragma unroll
      for (int i = 0; i < 4; i++)
#pragma unroll
        for (int j = 0; j < 6; j++) acc[i][j] += a[i] * b[j];
    }
    __syncthreads();
  }
  int ocol = c * FOUT + n0 + tx * 6;
#pragma unroll
  for (int i = 0; i < 4; i++) {
    int row = m0 + ty * 4 + i;
    if (row < NN) {
      float* o = out + (size_t)row * FOUT_TOTAL + ocol;
#pragma unroll
      for (int j = 0; j < 6; j++) o[j] += acc[i][j];
    }
  }
}

// ---------------- launch ----------------

extern "C" void kernel_launch(void* const* d_in, const int* in_sizes, int n_in,
                              void* d_out, int out_size, void* d_ws, size_t ws_size,
                              hipStream_t stream) {
  const float* x = (const float*)d_in[0];
  const int* ei = (const int*)d_in[1];
  const float* W[4] = {(const float*)d_in[2], (const float*)d_in[4],
                       (const float*)d_in[6], (const float*)d_in[8]};
  const float* b[4] = {(const float*)d_in[3], (const float*)d_in[5],
                       (const float*)d_in[7], (const float*)d_in[9]};
  float* out = (float*)d_out;

  char* ws = (char*)d_ws;
  size_t off = 0;
  auto alloc = [&](size_t bytes) -> char* {
    char* p = ws + off;
    off += (bytes + 255) & ~(size_t)255;
    return p;
  };
  int* deg = (int*)alloc(NN * 4);
  int* indeg = (int*)alloc(NN * 4);
  int* rowptr = (int*)alloc((NN + 1) * 4);
  int* cursor = (int*)alloc(NN * 4);
  int* srcarr = (int*)alloc(NE * 4);
  float* wn = (float*)alloc(NE * 4);
  float* dinv = (float*)alloc(NN * 4);
  float* bufA = (float*)alloc((size_t)NN * FIN * 4);
  float* bufB = (float*)alloc((size_t)NN * FIN * 4);

  hipMemsetAsync(deg, 0, NN * 4, stream);
  hipMemsetAsync(indeg, 0, NN * 4, stream);

  deg_kernel<<<(NE + 255) / 256, 256, 0, stream>>>(ei, deg, indeg);
  dinv_kernel<<<(NN + 255) / 256, 256, 0, stream>>>(deg, dinv);
  scan_kernel<<<1, 256, 0, stream>>>(indeg, rowptr, cursor);
  scatter_kernel<<<(NE + 255) / 256, 256, 0, stream>>>(ei, dinv, cursor, srcarr, wn);
  bias_init_kernel<<<(NN * FOUT_TOTAL + 255) / 256, 256, 0, stream>>>(out, b[0], b[1], b[2], b[3]);

  const size_t WSTRIDE = (size_t)FIN * FOUT; // per-k slice of a weight tensor
  auto gemm = [&](const float* T, int k) {
    int c0 = k - 3;
    if (c0 < 0) c0 = 0;
    int nconv = 4 - c0;
    dim3 grid((NN + BM - 1) / BM, FOUT / BN, nconv);
    gemm_acc_kernel<<<grid, 256, 0, stream>>>(
        T, W[0] + (size_t)k * WSTRIDE, W[1] + (size_t)k * WSTRIDE,
        W[2] + (size_t)k * WSTRIDE, W[3] + (size_t)k * WSTRIDE, out, c0);
  };

  // k = 0 : T0 = x
  gemm(x, 0);
  // T1 = prop(x)
  prop_kernel<<<NN / 2, 576, 0, stream>>>(x, x, bufA, rowptr, srcarr, wn, 1.0f, 0.0f);
  gemm(bufA, 1);
  // T2 = 2*prop(T1) - T0
  prop_kernel<<<NN / 2, 576, 0, stream>>>(bufA, x, bufB, rowptr, srcarr, wn, 2.0f, -1.0f);
  gemm(bufB, 2);
  // T3 = 2*prop(T2) - T1  (in-place over T1)
  prop_kernel<<<NN / 2, 576, 0, stream>>>(bufB, bufA, bufA, rowptr, srcarr, wn, 2.0f, -1.0f);
  gemm(bufA, 3);
  // T4 = 2*prop(T3) - T2  (in-place over T2)
  prop_kernel<<<NN / 2, 576, 0, stream>>>(bufA, bufB, bufB, rowptr, srcarr, wn, 2.0f, -1.0f);
  gemm(bufB, 4);
  // T5 = 2*prop(T4) - T3
  prop_kernel<<<NN / 2, 576, 0, stream>>>(bufB, bufA, bufA, rowptr, srcarr, wn, 2.0f, -1.0f);
  gemm(bufA, 5);
  // T6 = 2*prop(T5) - T4
  prop_kernel<<<NN / 2, 576, 0, stream>>>(bufA, bufB, bufB, rowptr, srcarr, wn, 2.0f, -1.0f);
  gemm(bufB, 6);
}

// Round 2
// 1306.326 us; speedup vs baseline: 2.3789x; 2.3789x over previous
//
#include <hip/hip_runtime.h>

#define NN 10000
#define NE 160000
#define FIN 1152
#define FOUT 288
#define FOUT_TOTAL 1152
#define WSL (FIN * FOUT) /* 331776 elements per (conv,k) weight slice */

typedef __attribute__((ext_vector_type(8))) short short8;
typedef __attribute__((ext_vector_type(4))) float floatx4;

__device__ __forceinline__ unsigned short f2bf(float f) {
  unsigned int u = __float_as_uint(f);
  u += 0x7FFF + ((u >> 16) & 1); // round-to-nearest-even
  return (unsigned short)(u >> 16);
}

// async global->LDS, 16B per lane. LDS dest MUST be wave-uniform base + lane*16.
__device__ __forceinline__ void async_copy16(void* lds, const void* gmem) {
  __builtin_amdgcn_global_load_lds(
      (const __attribute__((address_space(1))) unsigned int*)gmem,
      (__attribute__((address_space(3))) unsigned int*)lds, 16, 0, 0);
}

// ---------------- degree / normalization ----------------

__global__ void deg_kernel(const int* __restrict__ ei, int* __restrict__ deg,
                           int* __restrict__ indeg) {
  int e = blockIdx.x * 256 + threadIdx.x;
  if (e < NE) {
    atomicAdd(&deg[ei[e]], 1);        // out-degree by source (row)
    atomicAdd(&indeg[ei[NE + e]], 1); // in-degree by target (col)
  }
}

__global__ void dinv_kernel(const int* __restrict__ deg, float* __restrict__ dinv) {
  int i = blockIdx.x * 256 + threadIdx.x;
  if (i < NN) {
    int d = deg[i];
    dinv[i] = d > 0 ? rsqrtf((float)d) : 0.0f;
  }
}

// single-block exclusive scan of indeg -> rowptr (and cursor copy)
__global__ void scan_kernel(const int* __restrict__ indeg, int* __restrict__ rowptr,
                            int* __restrict__ cursor) {
  __shared__ int s[256];
  __shared__ int carry_s;
  if (threadIdx.x == 0) carry_s = 0;
  __syncthreads();
  for (int base = 0; base < NN; base += 256) {
    int i = base + threadIdx.x;
    int v = (i < NN) ? indeg[i] : 0;
    s[threadIdx.x] = v;
    __syncthreads();
    for (int off = 1; off < 256; off <<= 1) {
      int t = (threadIdx.x >= off) ? s[threadIdx.x - off] : 0;
      __syncthreads();
      s[threadIdx.x] += t;
      __syncthreads();
    }
    int excl = s[threadIdx.x] - v + carry_s;
    if (i < NN) { rowptr[i] = excl; cursor[i] = excl; }
    __syncthreads();
    if (threadIdx.x == 0) carry_s += s[255];
    __syncthreads();
  }
  if (threadIdx.x == 0) rowptr[NN] = carry_s;
}

__global__ void scatter_kernel(const int* __restrict__ ei, const float* __restrict__ dinv,
                               int* __restrict__ cursor, int* __restrict__ srcarr,
                               float* __restrict__ wn) {
  int e = blockIdx.x * 256 + threadIdx.x;
  if (e < NE) {
    int r = ei[e], c = ei[NE + e];
    int pos = atomicAdd(&cursor[c], 1);
    srcarr[pos] = r;
    wn[pos] = -(dinv[r] * dinv[c]);
  }
}

// ---------------- weight transpose+cast: Wt[slice][o][f] bf16 ----------------
__global__ void wtrans_kernel(const float* __restrict__ W0, const float* __restrict__ W1,
                              const float* __restrict__ W2, const float* __restrict__ W3,
                              unsigned short* __restrict__ Wt) {
  int i = blockIdx.x * 256 + threadIdx.x;
  if (i >= 22 * WSL) return;
  int s = i / WSL;
  int rem = i - s * WSL;
  int o = rem / FIN;
  int f = rem - o * FIN;
  int c, k;
  if (s < 4)       { c = 0; k = s; }
  else if (s < 9)  { c = 1; k = s - 4; }
  else if (s < 15) { c = 2; k = s - 9; }
  else             { c = 3; k = s - 15; }
  const float* W = (c == 0) ? W0 : (c == 1) ? W1 : (c == 2) ? W2 : W3;
  Wt[i] = f2bf(W[(size_t)k * WSL + (size_t)f * FOUT + o]);
}

// ---------------- x -> bf16 cast ----------------
__global__ void xcast_kernel(const float* __restrict__ x, unsigned short* __restrict__ Tb) {
  int i = blockIdx.x * 256 + threadIdx.x; // one float4 group per thread
  if (i < NN * FIN / 4) {
    float4 v = *(const float4*)(x + (size_t)i * 4);
    ushort4 r;
    r.x = f2bf(v.x); r.y = f2bf(v.y); r.z = f2bf(v.z); r.w = f2bf(v.w);
    *(ushort4*)(Tb + (size_t)i * 4) = r;
  }
}

// ---------------- propagation: dst = alpha*prop(H) + beta*Tprev; Tb = bf16(dst) -------
// 2 nodes per block, 288 float4 lanes per node. In-place safe when dst == Tprev.
__global__ __launch_bounds__(576) void prop_kernel(
    const float* __restrict__ H, const float* __restrict__ Tprev, float* __restrict__ dst,
    unsigned short* __restrict__ Tb,
    const int* __restrict__ rowptr, const int* __restrict__ srcarr,
    const float* __restrict__ wn, float alpha, float beta) {
  int t = threadIdx.x;
  int sub = (t >= 288) ? 1 : 0;
  int node = blockIdx.x * 2 + sub;
  int f4 = t - sub * 288; // 0..287
  int rs = rowptr[node];
  int re = rowptr[node + 1];
  float4 acc = make_float4(0.f, 0.f, 0.f, 0.f);
  for (int p = rs; p < re; ++p) {
    int r = srcarr[p];
    float w = wn[p];
    float4 h = *(const float4*)(H + (size_t)r * FIN + f4 * 4);
    acc.x += w * h.x; acc.y += w * h.y; acc.z += w * h.z; acc.w += w * h.w;
  }
  size_t o = (size_t)node * FIN + f4 * 4;
  float4 res;
  if (beta != 0.0f) {
    float4 tp = *(const float4*)(Tprev + o);
    res.x = alpha * acc.x + beta * tp.x;
    res.y = alpha * acc.y + beta * tp.y;
    res.z = alpha * acc.z + beta * tp.z;
    res.w = alpha * acc.w + beta * tp.w;
  } else {
    res.x = alpha * acc.x; res.y = alpha * acc.y;
    res.z = alpha * acc.z; res.w = alpha * acc.w;
  }
  *(float4*)(dst + o) = res;
  ushort4 rb;
  rb.x = f2bf(res.x); rb.y = f2bf(res.y); rb.z = f2bf(res.z); rb.w = f2bf(res.w);
  *(ushort4*)(Tb + o) = rb;
}

// ---------------- bias init ----------------
__global__ void bias_init_kernel(float* __restrict__ out, const float* __restrict__ b0,
                                 const float* __restrict__ b1, const float* __restrict__ b2,
                                 const float* __restrict__ b3) {
  int i = blockIdx.x * 256 + threadIdx.x;
  if (i < NN * FOUT_TOTAL) {
    int j = i % FOUT_TOTAL;
    int c = j / FOUT;
    const float* b = (c == 0) ? b0 : (c == 1) ? b1 : (c == 2) ? b2 : b3;
    out[i] = b[j - c * FOUT];
  }
}

// ---------------- MFMA GEMM accumulate: out[:, c*288+n0 : +96] += Tb @ Wt[slice]^T ----
// Block tile 128x96, K=1152 (BK=64), 4 waves in 2x2, wave tile 64x48 = 4x3 mfma frags.
__global__ __launch_bounds__(256) void gemm_mfma_kernel(
    const unsigned short* __restrict__ Tb, const unsigned short* __restrict__ Wt,
    float* __restrict__ out, int kidx, int c0) {
  const int c = c0 + blockIdx.z;
  const int slice = ((c * c + 7 * c) >> 1) + kidx; // cumstart{0,4,9,15}[c] + kidx
  const int m0 = blockIdx.x * 128;
  const int n0 = blockIdx.y * 96;

  __shared__ unsigned short As[128][64]; // [m][k] rows of 128 B
  __shared__ unsigned short Bs[96][64];  // [o][f] rows of 128 B

  const int tid = threadIdx.x;
  const int lane = tid & 63;
  const int wave = tid >> 6;
  const int wx = wave & 1;        // n-dir
  const int wy = wave >> 1;       // m-dir
  const int lm = lane & 15;
  const int lkb = (lane >> 4) * 8; // k sub-offset within 32

  floatx4 acc[4][3];
#pragma unroll
  for (int i = 0; i < 4; i++)
#pragma unroll
    for (int j = 0; j < 3; j++) acc[i][j] = (floatx4){0.f, 0.f, 0.f, 0.f};

  const unsigned short* Wbase = Wt + (size_t)slice * WSL;

  for (int f0 = 0; f0 < FIN; f0 += 64) {
    __syncthreads(); // protect LDS from previous iteration's readers
    // stage A: 128 rows x 128 B, lane-linear LDS
#pragma unroll
    for (int i = 0; i < 4; i++) {
      int idx = i * 256 + tid;
      int row = idx >> 3;
      int cb = (idx & 7) * 16;
      int gr = m0 + row;
      gr = gr < NN ? gr : NN - 1; // clamp (masked at store)
      async_copy16((char*)&As[0][0] + idx * 16,
                   (const char*)Tb + ((size_t)gr * FIN + f0) * 2 + cb);
    }
    // stage B: 96 rows x 128 B
#pragma unroll
    for (int i = 0; i < 3; i++) {
      int idx = i * 256 + tid;
      int row = idx >> 3;
      int cb = (idx & 7) * 16;
      async_copy16((char*)&Bs[0][0] + idx * 16,
                   (const char*)Wbase + ((size_t)(n0 + row) * FIN + f0) * 2 + cb);
    }
    __syncthreads();
#pragma unroll
    for (int s = 0; s < 2; s++) {
      short8 a[4], b[3];
#pragma unroll
      for (int i = 0; i < 4; i++)
        a[i] = *(const short8*)&As[wy * 64 + i * 16 + lm][s * 32 + lkb];
#pragma unroll
      for (int j = 0; j < 3; j++)
        b[j] = *(const short8*)&Bs[wx * 48 + j * 16 + lm][s * 32 + lkb];
#pragma unroll
      for (int i = 0; i < 4; i++)
#pragma unroll
        for (int j = 0; j < 3; j++)
          acc[i][j] = __builtin_amdgcn_mfma_f32_16x16x32_bf16(a[i], b[j], acc[i][j], 0, 0, 0);
    }
  }
  // epilogue: C/D layout col=lane&15, row=(lane>>4)*4+reg
  const int cbase = c * FOUT + n0 + wx * 48;
  const int rbase = (lane >> 4) * 4;
#pragma unroll
  for (int i = 0; i < 4; i++) {
#pragma unroll
    for (int r = 0; r < 4; r++) {
      int grow = m0 + wy * 64 + i * 16 + rbase + r;
      if (grow < NN) {
        float* op = out + (size_t)grow * FOUT_TOTAL + cbase + lm;
#pragma unroll
        for (int j = 0; j < 3; j++) op[j * 16] += acc[i][j][r];
      }
    }
  }
}

// ---------------- launch ----------------

extern "C" void kernel_launch(void* const* d_in, const int* in_sizes, int n_in,
                              void* d_out, int out_size, void* d_ws, size_t ws_size,
                              hipStream_t stream) {
  const float* x = (const float*)d_in[0];
  const int* ei = (const int*)d_in[1];
  const float* W[4] = {(const float*)d_in[2], (const float*)d_in[4],
                       (const float*)d_in[6], (const float*)d_in[8]};
  const float* b[4] = {(const float*)d_in[3], (const float*)d_in[5],
                       (const float*)d_in[7], (const float*)d_in[9]};
  float* out = (float*)d_out;

  char* ws = (char*)d_ws;
  size_t off = 0;
  auto alloc = [&](size_t bytes) -> char* {
    char* p = ws + off;
    off += (bytes + 255) & ~(size_t)255;
    return p;
  };
  int* deg = (int*)alloc(NN * 4);
  int* indeg = (int*)alloc(NN * 4);
  int* rowptr = (int*)alloc((NN + 1) * 4);
  int* cursor = (int*)alloc(NN * 4);
  int* srcarr = (int*)alloc(NE * 4);
  float* wn = (float*)alloc(NE * 4);
  float* dinv = (float*)alloc(NN * 4);
  float* bufA = (float*)alloc((size_t)NN * FIN * 4);
  float* bufB = (float*)alloc((size_t)NN * FIN * 4);
  unsigned short* Tb = (unsigned short*)alloc((size_t)NN * FIN * 2);   // bf16 T_k
  unsigned short* Wt = (unsigned short*)alloc((size_t)22 * WSL * 2);   // bf16 W^T

  hipMemsetAsync(deg, 0, NN * 4, stream);
  hipMemsetAsync(indeg, 0, NN * 4, stream);

  deg_kernel<<<(NE + 255) / 256, 256, 0, stream>>>(ei, deg, indeg);
  dinv_kernel<<<(NN + 255) / 256, 256, 0, stream>>>(deg, dinv);
  scan_kernel<<<1, 256, 0, stream>>>(indeg, rowptr, cursor);
  scatter_kernel<<<(NE + 255) / 256, 256, 0, stream>>>(ei, dinv, cursor, srcarr, wn);
  wtrans_kernel<<<(22 * WSL + 255) / 256, 256, 0, stream>>>(W[0], W[1], W[2], W[3], Wt);
  xcast_kernel<<<(NN * FIN / 4 + 255) / 256, 256, 0, stream>>>(x, Tb);
  bias_init_kernel<<<(NN * FOUT_TOTAL + 255) / 256, 256, 0, stream>>>(out, b[0], b[1], b[2], b[3]);

  auto gemm = [&](int k) {
    int c0 = k - 3;
    if (c0 < 0) c0 = 0;
    int nconv = 4 - c0;
    dim3 grid((NN + 127) / 128, FOUT / 96, nconv);
    gemm_mfma_kernel<<<grid, 256, 0, stream>>>(Tb, Wt, out, k, c0);
  };

  // k = 0 : T0 = x (already cast into Tb)
  gemm(0);
  // T1 = prop(x)
  prop_kernel<<<NN / 2, 576, 0, stream>>>(x, x, bufA, Tb, rowptr, srcarr, wn, 1.0f, 0.0f);
  gemm(1);
  // T2 = 2*prop(T1) - T0
  prop_kernel<<<NN / 2, 576, 0, stream>>>(bufA, x, bufB, Tb, rowptr, srcarr, wn, 2.0f, -1.0f);
  gemm(2);
  // T3 = 2*prop(T2) - T1  (in-place over T1)
  prop_kernel<<<NN / 2, 576, 0, stream>>>(bufB, bufA, bufA, Tb, rowptr, srcarr, wn, 2.0f, -1.0f);
  gemm(3);
  // T4 = 2*prop(T3) - T2  (in-place over T2)
  prop_kernel<<<NN / 2, 576, 0, stream>>>(bufA, bufB, bufB, Tb, rowptr, srcarr, wn, 2.0f, -1.0f);
  gemm(4);
  // T5 = 2*prop(T4) - T3
  prop_kernel<<<NN / 2, 576, 0, stream>>>(bufB, bufA, bufA, Tb, rowptr, srcarr, wn, 2.0f, -1.0f);
  gemm(5);
  // T6 = 2*prop(T5) - T4
  prop_kernel<<<NN / 2, 576, 0, stream>>>(bufA, bufB, bufB, Tb, rowptr, srcarr, wn, 2.0f, -1.0f);
  gemm(6);
}

// Round 3
// 800.411 us; speedup vs baseline: 3.8826x; 1.6321x over previous
//
#include <hip/hip_runtime.h>

#define NN 10000
#define NE 160000
#define FIN 1152
#define FOUT 288
#define FOUT_TOTAL 1152
#define NF (NN * FOUT)          /* 2,880,000 elems per N x 288 panel */
#define WSL (FIN * FOUT)        /* 331,776 elems per (conv,k) weight slice */
#define NSLICE 22

typedef __attribute__((ext_vector_type(8))) short short8;
typedef __attribute__((ext_vector_type(8))) unsigned short ushort8v;
typedef __attribute__((ext_vector_type(4))) float floatx4;

__device__ __forceinline__ unsigned short f2bf(float f) {
  unsigned int u = __float_as_uint(f);
  u += 0x7FFF + ((u >> 16) & 1); // round-to-nearest-even
  return (unsigned short)(u >> 16);
}
__device__ __forceinline__ float bf2f(unsigned short u) {
  return __uint_as_float(((unsigned int)u) << 16);
}

// async global->LDS, 16B per lane. LDS dest MUST be wave-uniform base + lane*16.
__device__ __forceinline__ void async_copy16(void* lds, const void* gmem) {
  __builtin_amdgcn_global_load_lds(
      (const __attribute__((address_space(1))) unsigned int*)gmem,
      (__attribute__((address_space(3))) unsigned int*)lds, 16, 0, 0);
}

// ---------------- degree / normalization ----------------

__global__ void deg_kernel(const int* __restrict__ ei, int* __restrict__ deg,
                           int* __restrict__ indeg) {
  int e = blockIdx.x * 256 + threadIdx.x;
  if (e < NE) {
    atomicAdd(&deg[ei[e]], 1);        // out-degree by source (row)
    atomicAdd(&indeg[ei[NE + e]], 1); // in-degree by target (col)
  }
}

__global__ void dinv_kernel(const int* __restrict__ deg, float* __restrict__ dinv) {
  int i = blockIdx.x * 256 + threadIdx.x;
  if (i < NN) {
    int d = deg[i];
    dinv[i] = d > 0 ? rsqrtf((float)d) : 0.0f;
  }
}

// single-block exclusive scan of indeg -> rowptr (and cursor copy)
__global__ void scan_kernel(const int* __restrict__ indeg, int* __restrict__ rowptr,
                            int* __restrict__ cursor) {
  __shared__ int s[256];
  __shared__ int carry_s;
  if (threadIdx.x == 0) carry_s = 0;
  __syncthreads();
  for (int base = 0; base < NN; base += 256) {
    int i = base + threadIdx.x;
    int v = (i < NN) ? indeg[i] : 0;
    s[threadIdx.x] = v;
    __syncthreads();
    for (int off = 1; off < 256; off <<= 1) {
      int t = (threadIdx.x >= off) ? s[threadIdx.x - off] : 0;
      __syncthreads();
      s[threadIdx.x] += t;
      __syncthreads();
    }
    int excl = s[threadIdx.x] - v + carry_s;
    if (i < NN) { rowptr[i] = excl; cursor[i] = excl; }
    __syncthreads();
    if (threadIdx.x == 0) carry_s += s[255];
    __syncthreads();
  }
  if (threadIdx.x == 0) rowptr[NN] = carry_s;
}

__global__ void scatter_kernel(const int* __restrict__ ei, const float* __restrict__ dinv,
                               int* __restrict__ cursor, int* __restrict__ srcarr,
                               float* __restrict__ wn) {
  int e = blockIdx.x * 256 + threadIdx.x;
  if (e < NE) {
    int r = ei[e], c = ei[NE + e];
    int pos = atomicAdd(&cursor[c], 1);
    srcarr[pos] = r;
    wn[pos] = -(dinv[r] * dinv[c]);
  }
}

// ---------------- weight transpose+cast: Wt[slice][o][f] bf16 ----------------
__global__ void wtrans_kernel(const float* __restrict__ W0, const float* __restrict__ W1,
                              const float* __restrict__ W2, const float* __restrict__ W3,
                              unsigned short* __restrict__ Wt) {
  int i = blockIdx.x * 256 + threadIdx.x;
  if (i >= NSLICE * WSL) return;
  int s = i / WSL;
  int rem = i - s * WSL;
  int o = rem / FIN;
  int f = rem - o * FIN;
  int c, k;
  if (s < 4)       { c = 0; k = s; }
  else if (s < 9)  { c = 1; k = s - 4; }
  else if (s < 15) { c = 2; k = s - 9; }
  else             { c = 3; k = s - 15; }
  const float* W = (c == 0) ? W0 : (c == 1) ? W1 : (c == 2) ? W2 : W3;
  Wt[i] = f2bf(W[(size_t)k * WSL + (size_t)f * FOUT + o]);
}

// ---------------- x -> bf16 cast ----------------
__global__ void xcast_kernel(const float* __restrict__ x, unsigned short* __restrict__ xb) {
  int i = blockIdx.x * 256 + threadIdx.x; // one float4 group per thread
  if (i < NN * FIN / 4) {
    float4 v = *(const float4*)(x + (size_t)i * 4);
    ushort4 r;
    r.x = f2bf(v.x); r.y = f2bf(v.y); r.z = f2bf(v.z); r.w = f2bf(v.w);
    *(ushort4*)(xb + (size_t)i * 4) = r;
  }
}

// ---------------- MFMA GEMM: Y[slice] = bf16( xb @ Wt[slice]^T ) ----------------
// Block tile 128x96, K=1152 (BK=64), 4 waves in 2x2, wave tile 64x48 = 4x3 mfma frags.
__global__ __launch_bounds__(256) void gemm_mfma_kernel(
    const unsigned short* __restrict__ Xb, const unsigned short* __restrict__ Wt,
    unsigned short* __restrict__ Yall) {
  const int slice = blockIdx.z;
  const int m0 = blockIdx.x * 128;
  const int n0 = blockIdx.y * 96;

  __shared__ unsigned short As[128][64]; // [m][k] rows of 128 B
  __shared__ unsigned short Bs[96][64];  // [o][f] rows of 128 B

  const int tid = threadIdx.x;
  const int lane = tid & 63;
  const int wave = tid >> 6;
  const int wx = wave & 1;        // n-dir
  const int wy = wave >> 1;       // m-dir
  const int lm = lane & 15;
  const int lkb = (lane >> 4) * 8; // k sub-offset within 32

  floatx4 acc[4][3];
#pragma unroll
  for (int i = 0; i < 4; i++)
#pragma unroll
    for (int j = 0; j < 3; j++) acc[i][j] = (floatx4){0.f, 0.f, 0.f, 0.f};

  const unsigned short* Wbase = Wt + (size_t)slice * WSL;

  for (int f0 = 0; f0 < FIN; f0 += 64) {
    __syncthreads(); // protect LDS from previous iteration's readers
    // stage A: 128 rows x 128 B, lane-linear LDS
#pragma unroll
    for (int i = 0; i < 4; i++) {
      int idx = i * 256 + tid;
      int row = idx >> 3;
      int cb = (idx & 7) * 16;
      int gr = m0 + row;
      gr = gr < NN ? gr : NN - 1; // clamp (masked at store)
      async_copy16((char*)&As[0][0] + idx * 16,
                   (const char*)Xb + ((size_t)gr * FIN + f0) * 2 + cb);
    }
    // stage B: 96 rows x 128 B
#pragma unroll
    for (int i = 0; i < 3; i++) {
      int idx = i * 256 + tid;
      int row = idx >> 3;
      int cb = (idx & 7) * 16;
      async_copy16((char*)&Bs[0][0] + idx * 16,
                   (const char*)Wbase + ((size_t)(n0 + row) * FIN + f0) * 2 + cb);
    }
    __syncthreads();
#pragma unroll
    for (int s = 0; s < 2; s++) {
      short8 a[4], b[3];
#pragma unroll
      for (int i = 0; i < 4; i++)
        a[i] = *(const short8*)&As[wy * 64 + i * 16 + lm][s * 32 + lkb];
#pragma unroll
      for (int j = 0; j < 3; j++)
        b[j] = *(const short8*)&Bs[wx * 48 + j * 16 + lm][s * 32 + lkb];
#pragma unroll
      for (int i = 0; i < 4; i++)
#pragma unroll
        for (int j = 0; j < 3; j++)
          acc[i][j] = __builtin_amdgcn_mfma_f32_16x16x32_bf16(a[i], b[j], acc[i][j], 0, 0, 0);
    }
  }
  // epilogue: C/D layout col=lane&15, row=(lane>>4)*4+reg -> bf16 Y panel
  unsigned short* Yb = Yall + (size_t)slice * NF;
  const int cbase = n0 + wx * 48 + lm;
  const int rbase = (lane >> 4) * 4;
#pragma unroll
  for (int i = 0; i < 4; i++) {
#pragma unroll
    for (int r = 0; r < 4; r++) {
      int grow = m0 + wy * 64 + i * 16 + rbase + r;
      if (grow < NN) {
        unsigned short* op = Yb + (size_t)grow * FOUT + cbase;
#pragma unroll
        for (int j = 0; j < 3; j++) op[j * 16] = f2bf(acc[i][j][r]);
      }
    }
  }
}

// ---------------- Clenshaw steps ----------------
// b_k = Y_k + 2*L*b_{k+1} - b_{k+2}   (all N x 288 bf16 panels; fp32 accumulate)
// In-place: D may equal P (same element read-then-written by its own thread).
// Block: 576 threads = 16 nodes x 36 lanes, 16B (8 bf16) per lane.

struct StepArgs {
  const unsigned short* H[4]; // gather source  b_{k+1}
  const unsigned short* Y[4]; // additive Y_k
  const unsigned short* P[4]; // b_{k+2} (may be null)
  unsigned short* D[4];       // dest b_k
};

__global__ __launch_bounds__(576) void cl_step_kernel(
    StepArgs a, const int* __restrict__ rowptr, const int* __restrict__ srcarr,
    const float* __restrict__ wn) {
  const int slot = blockIdx.y;
  const unsigned short* __restrict__ H = a.H[slot];
  const int t = threadIdx.x;
  const int ln = t % 36;
  const int node = blockIdx.x * 16 + t / 36;
  if (node >= NN) return;
  const int off = ln * 8;
  const int rs = rowptr[node];
  const int re = rowptr[node + 1];
  float acc[8];
#pragma unroll
  for (int q = 0; q < 8; q++) acc[q] = 0.f;
  for (int p = rs; p < re; ++p) {
    int r = srcarr[p];
    float w = wn[p];
    ushort8v h = *(const ushort8v*)(H + (size_t)r * FOUT + off);
#pragma unroll
    for (int q = 0; q < 8; q++) acc[q] += w * bf2f(h[q]);
  }
  size_t o = (size_t)node * FOUT + off;
  ushort8v y = *(const ushort8v*)(a.Y[slot] + o);
  ushort8v d;
  if (a.P[slot]) {
    ushort8v pp = *(const ushort8v*)(a.P[slot] + o);
#pragma unroll
    for (int q = 0; q < 8; q++) d[q] = f2bf(bf2f(y[q]) + 2.f * acc[q] - bf2f(pp[q]));
  } else {
#pragma unroll
    for (int q = 0; q < 8; q++) d[q] = f2bf(bf2f(y[q]) + 2.f * acc[q]);
  }
  *(ushort8v*)(a.D[slot] + o) = d;
}

// final: out[:, c*288 + f] = bias[f] + Y_0 + L*b_1 - b_2   (fp32 out)
struct FinalArgs {
  const unsigned short* H[4]; // b_1
  const unsigned short* Y[4]; // Y_0
  const unsigned short* P[4]; // b_2
  const float* B[4];          // bias
  int conv[4];
};

__global__ __launch_bounds__(576) void cl_final_kernel(
    FinalArgs a, const int* __restrict__ rowptr, const int* __restrict__ srcarr,
    const float* __restrict__ wn, float* __restrict__ out) {
  const int slot = blockIdx.y;
  const unsigned short* __restrict__ H = a.H[slot];
  const int t = threadIdx.x;
  const int ln = t % 36;
  const int node = blockIdx.x * 16 + t / 36;
  if (node >= NN) return;
  const int off = ln * 8;
  const int rs = rowptr[node];
  const int re = rowptr[node + 1];
  float acc[8];
#pragma unroll
  for (int q = 0; q < 8; q++) acc[q] = 0.f;
  for (int p = rs; p < re; ++p) {
    int r = srcarr[p];
    float w = wn[p];
    ushort8v h = *(const ushort8v*)(H + (size_t)r * FOUT + off);
#pragma unroll
    for (int q = 0; q < 8; q++) acc[q] += w * bf2f(h[q]);
  }
  size_t o = (size_t)node * FOUT + off;
  ushort8v y = *(const ushort8v*)(a.Y[slot] + o);
  ushort8v pp = *(const ushort8v*)(a.P[slot] + o);
  const float* bias = a.B[slot] + off;
  float r8[8];
#pragma unroll
  for (int q = 0; q < 8; q++)
    r8[q] = bias[q] + bf2f(y[q]) + acc[q] - bf2f(pp[q]);
  float* op = out + (size_t)node * FOUT_TOTAL + a.conv[slot] * FOUT + off;
  *(float4*)(op + 0) = make_float4(r8[0], r8[1], r8[2], r8[3]);
  *(float4*)(op + 4) = make_float4(r8[4], r8[5], r8[6], r8[7]);
}

// ---------------- launch ----------------

extern "C" void kernel_launch(void* const* d_in, const int* in_sizes, int n_in,
                              void* d_out, int out_size, void* d_ws, size_t ws_size,
                              hipStream_t stream) {
  const float* x = (const float*)d_in[0];
  const int* ei = (const int*)d_in[1];
  const float* W[4] = {(const float*)d_in[2], (const float*)d_in[4],
                       (const float*)d_in[6], (const float*)d_in[8]};
  const float* b[4] = {(const float*)d_in[3], (const float*)d_in[5],
                       (const float*)d_in[7], (const float*)d_in[9]};
  float* out = (float*)d_out;

  char* ws = (char*)d_ws;
  size_t off = 0;
  auto alloc = [&](size_t bytes) -> char* {
    char* p = ws + off;
    off += (bytes + 255) & ~(size_t)255;
    return p;
  };
  int* deg = (int*)alloc(NN * 4);
  int* indeg = (int*)alloc(NN * 4);
  int* rowptr = (int*)alloc((NN + 1) * 4);
  int* cursor = (int*)alloc(NN * 4);
  int* srcarr = (int*)alloc(NE * 4);
  float* wn = (float*)alloc(NE * 4);
  float* dinv = (float*)alloc(NN * 4);
  unsigned short* xb = (unsigned short*)alloc((size_t)NN * FIN * 2);       // bf16 x; reused as 4 spare panels
  unsigned short* Wt = (unsigned short*)alloc((size_t)NSLICE * WSL * 2);   // bf16 W^T
  unsigned short* Yall = (unsigned short*)alloc((size_t)NSLICE * NF * 2);  // bf16 Y panels

  hipMemsetAsync(deg, 0, NN * 4, stream);
  hipMemsetAsync(indeg, 0, NN * 4, stream);

  deg_kernel<<<(NE + 255) / 256, 256, 0, stream>>>(ei, deg, indeg);
  dinv_kernel<<<(NN + 255) / 256, 256, 0, stream>>>(deg, dinv);
  scan_kernel<<<1, 256, 0, stream>>>(indeg, rowptr, cursor);
  scatter_kernel<<<(NE + 255) / 256, 256, 0, stream>>>(ei, dinv, cursor, srcarr, wn);
  wtrans_kernel<<<(NSLICE * WSL + 255) / 256, 256, 0, stream>>>(W[0], W[1], W[2], W[3], Wt);
  xcast_kernel<<<(NN * FIN / 4 + 255) / 256, 256, 0, stream>>>(x, xb);

  // all 22 GEMMs in one dispatch
  {
    dim3 grid((NN + 127) / 128, FOUT / 96, NSLICE);
    gemm_mfma_kernel<<<grid, 256, 0, stream>>>(xb, Wt, Yall);
  }

  // ---- Clenshaw schedule (host-side bookkeeping) ----
  const int nK[4] = {4, 5, 6, 7};
  const int st[4] = {0, 4, 9, 15};
  unsigned short* S[4]; // spare panels alias xb (xb no longer needed after GEMM)
  for (int c = 0; c < 4; c++) S[c] = xb + (size_t)c * NF;

  StepArgs sched[5];
  int nact[5] = {0, 0, 0, 0, 0};
  FinalArgs fa;

  for (int c = 3; c >= 0; c--) {
    int n = nK[c] - 1;        // Clenshaw degree (props per conv)
    int s0 = 6 - n;           // first global step for this conv
    unsigned short* Yn = Yall + (size_t)(st[c] + n) * NF; // holds b_n = Y_n initially
    unsigned short* A = S[c];
    for (int p = 1; p <= n; p++) {
      int s = s0 + p - 1;
      if (p < n) {
        unsigned short* H = (p & 1) ? Yn : A;
        unsigned short* D = (p & 1) ? A : Yn;
        int j = nact[s]++;
        sched[s].H[j] = H;
        sched[s].Y[j] = Yall + (size_t)(st[c] + n - p) * NF;
        sched[s].P[j] = (p == 1) ? nullptr : D; // in-place over b_{k+2}
        sched[s].D[j] = D;
      } else { // final at s == 5
        int j = 3 - c;
        fa.H[j] = ((n - 1) & 1) ? A : Yn; // loc(b_1)
        fa.P[j] = ((n - 2) & 1) ? A : Yn; // loc(b_2)
        fa.Y[j] = Yall + (size_t)st[c] * NF;
        fa.B[j] = b[c];
        fa.conv[j] = c;
      }
    }
  }

  for (int s = 0; s < 5; s++) {
    cl_step_kernel<<<dim3(NN / 16, nact[s]), 576, 0, stream>>>(sched[s], rowptr, srcarr, wn);
  }
  cl_final_kernel<<<dim3(NN / 16, 4), 576, 0, stream>>>(fa, rowptr, srcarr, wn, out);
}

// Round 7
// 770.085 us; speedup vs baseline: 4.0355x; 1.0394x over previous
//
#include <hip/hip_runtime.h>

#define NN 10000
#define NE 160000
#define FIN 1152
#define FOUT 288
#define FOUT_TOTAL 1152
#define NF (NN * FOUT)          /* 2,880,000 elems per N x 288 panel */
#define WSL (FIN * FOUT)        /* 331,776 elems per (conv,k) weight slice */
#define NSLICE 22

typedef __attribute__((ext_vector_type(8))) short short8;
typedef __attribute__((ext_vector_type(8))) unsigned short ushort8v;
typedef __attribute__((ext_vector_type(4))) float floatx4;

__device__ __forceinline__ unsigned short f2bf(float f) {
  unsigned int u = __float_as_uint(f);
  u += 0x7FFF + ((u >> 16) & 1); // round-to-nearest-even
  return (unsigned short)(u >> 16);
}
__device__ __forceinline__ float bf2f(unsigned short u) {
  return __uint_as_float(((unsigned int)u) << 16);
}

// async global->LDS, 16B per lane. LDS dest MUST be wave-uniform base + lane*16.
__device__ __forceinline__ void async_copy16(void* lds, const void* gmem) {
  __builtin_amdgcn_global_load_lds(
      (const __attribute__((address_space(1))) unsigned int*)gmem,
      (__attribute__((address_space(3))) unsigned int*)lds, 16, 0, 0);
}

// ---------------- degree / normalization ----------------

__global__ void deg_kernel(const int* __restrict__ ei, int* __restrict__ deg,
                           int* __restrict__ indeg) {
  int e = blockIdx.x * 256 + threadIdx.x;
  if (e < NE) {
    atomicAdd(&deg[ei[e]], 1);        // out-degree by source (row)
    atomicAdd(&indeg[ei[NE + e]], 1); // in-degree by target (col)
  }
}

__global__ void dinv_kernel(const int* __restrict__ deg, float* __restrict__ dinv) {
  int i = blockIdx.x * 256 + threadIdx.x;
  if (i < NN) {
    int d = deg[i];
    dinv[i] = d > 0 ? rsqrtf((float)d) : 0.0f;
  }
}

// single-block exclusive scan of indeg -> rowptr (and cursor copy)
__global__ void scan_kernel(const int* __restrict__ indeg, int* __restrict__ rowptr,
                            int* __restrict__ cursor) {
  __shared__ int s[256];
  __shared__ int carry_s;
  if (threadIdx.x == 0) carry_s = 0;
  __syncthreads();
  for (int base = 0; base < NN; base += 256) {
    int i = base + threadIdx.x;
    int v = (i < NN) ? indeg[i] : 0;
    s[threadIdx.x] = v;
    __syncthreads();
    for (int off = 1; off < 256; off <<= 1) {
      int t = (threadIdx.x >= off) ? s[threadIdx.x - off] : 0;
      __syncthreads();
      s[threadIdx.x] += t;
      __syncthreads();
    }
    int excl = s[threadIdx.x] - v + carry_s;
    if (i < NN) { rowptr[i] = excl; cursor[i] = excl; }
    __syncthreads();
    if (threadIdx.x == 0) carry_s += s[255];
    __syncthreads();
  }
  if (threadIdx.x == 0) rowptr[NN] = carry_s;
}

__global__ void scatter_kernel(const int* __restrict__ ei, const float* __restrict__ dinv,
                               int* __restrict__ cursor, int* __restrict__ srcarr,
                               float* __restrict__ wn) {
  int e = blockIdx.x * 256 + threadIdx.x;
  if (e < NE) {
    int r = ei[e], c = ei[NE + e];
    int pos = atomicAdd(&cursor[c], 1);
    srcarr[pos] = r;
    wn[pos] = -(dinv[r] * dinv[c]);
  }
}

// ---------------- weight transpose+cast: Wt[slice][o][f] bf16 ----------------
__global__ void wtrans_kernel(const float* __restrict__ W0, const float* __restrict__ W1,
                              const float* __restrict__ W2, const float* __restrict__ W3,
                              unsigned short* __restrict__ Wt) {
  int i = blockIdx.x * 256 + threadIdx.x;
  if (i >= NSLICE * WSL) return;
  int s = i / WSL;
  int rem = i - s * WSL;
  int o = rem / FIN;
  int f = rem - o * FIN;
  int c, k;
  if (s < 4)       { c = 0; k = s; }
  else if (s < 9)  { c = 1; k = s - 4; }
  else if (s < 15) { c = 2; k = s - 9; }
  else             { c = 3; k = s - 15; }
  const float* W = (c == 0) ? W0 : (c == 1) ? W1 : (c == 2) ? W2 : W3;
  Wt[i] = f2bf(W[(size_t)k * WSL + (size_t)f * FOUT + o]);
}

// ---------------- x -> bf16 cast ----------------
__global__ void xcast_kernel(const float* __restrict__ x, unsigned short* __restrict__ xb) {
  int i = blockIdx.x * 256 + threadIdx.x; // one float4 group per thread
  if (i < NN * FIN / 4) {
    float4 v = *(const float4*)(x + (size_t)i * 4);
    ushort4 r;
    r.x = f2bf(v.x); r.y = f2bf(v.y); r.z = f2bf(v.z); r.w = f2bf(v.w);
    *(ushort4*)(xb + (size_t)i * 4) = r;
  }
}

// ---------------- MFMA GEMM: Y[slice] = bf16( xb @ Wt[slice]^T ) ----------------
// Block tile 128x96, K=1152 (BK=64), 4 waves in 2x2, wave tile 64x48 = 4x3 mfma frags.
// Grid: x = (slice, ntile) [66], y = mtile [79] -> 66 consecutive blocks share one
// A-tile (L2 reuse); weight set (14.6 MB) stays L2-resident across the y sweep.
// NOTE: identical to the R3 kernel except the blockIdx mapping (one-variable diff).
__global__ __launch_bounds__(256) void gemm_mfma_kernel(
    const unsigned short* __restrict__ Xb, const unsigned short* __restrict__ Wt,
    unsigned short* __restrict__ Yall) {
  const int bx = blockIdx.x;
  const int slice = bx / 3;
  const int n0 = (bx - slice * 3) * 96;
  const int m0 = blockIdx.y * 128;

  __shared__ unsigned short As[128][64]; // [m][k] rows of 128 B
  __shared__ unsigned short Bs[96][64];  // [o][f]

  const int tid = threadIdx.x;
  const int lane = tid & 63;
  const int wave = tid >> 6;
  const int wx = wave & 1;        // n-dir
  const int wy = wave >> 1;       // m-dir
  const int lm = lane & 15;
  const int lkb = (lane >> 4) * 8; // k sub-offset within 32

  floatx4 acc[4][3];
#pragma unroll
  for (int i = 0; i < 4; i++)
#pragma unroll
    for (int j = 0; j < 3; j++) acc[i][j] = (floatx4){0.f, 0.f, 0.f, 0.f};

  const unsigned short* Wbase = Wt + (size_t)slice * WSL;

  for (int f0 = 0; f0 < FIN; f0 += 64) {
    __syncthreads(); // protect LDS from previous iteration's readers
    // stage A: 128 rows x 128 B, lane-linear LDS
#pragma unroll
    for (int i = 0; i < 4; i++) {
      int idx = i * 256 + tid;
      int row = idx >> 3;
      int cb = (idx & 7) * 16;
      int gr = m0 + row;
      gr = gr < NN ? gr : NN - 1; // clamp (masked at store)
      async_copy16((char*)&As[0][0] + idx * 16,
                   (const char*)Xb + ((size_t)gr * FIN + f0) * 2 + cb);
    }
    // stage B: 96 rows x 128 B
#pragma unroll
    for (int i = 0; i < 3; i++) {
      int idx = i * 256 + tid;
      int row = idx >> 3;
      int cb = (idx & 7) * 16;
      async_copy16((char*)&Bs[0][0] + idx * 16,
                   (const char*)Wbase + ((size_t)(n0 + row) * FIN + f0) * 2 + cb);
    }
    __syncthreads();
#pragma unroll
    for (int s = 0; s < 2; s++) {
      short8 a[4], b[3];
#pragma unroll
      for (int i = 0; i < 4; i++)
        a[i] = *(const short8*)&As[wy * 64 + i * 16 + lm][s * 32 + lkb];
#pragma unroll
      for (int j = 0; j < 3; j++)
        b[j] = *(const short8*)&Bs[wx * 48 + j * 16 + lm][s * 32 + lkb];
#pragma unroll
      for (int i = 0; i < 4; i++)
#pragma unroll
        for (int j = 0; j < 3; j++)
          acc[i][j] = __builtin_amdgcn_mfma_f32_16x16x32_bf16(a[i], b[j], acc[i][j], 0, 0, 0);
    }
  }
  // epilogue: C/D layout col=lane&15, row=(lane>>4)*4+reg -> bf16 Y panel
  unsigned short* Yb = Yall + (size_t)slice * NF;
  const int cbase = n0 + wx * 48 + lm;
  const int rbase = (lane >> 4) * 4;
#pragma unroll
  for (int i = 0; i < 4; i++) {
#pragma unroll
    for (int r = 0; r < 4; r++) {
      int grow = m0 + wy * 64 + i * 16 + rbase + r;
      if (grow < NN) {
        unsigned short* op = Yb + (size_t)grow * FOUT + cbase;
#pragma unroll
        for (int j = 0; j < 3; j++) op[j * 16] = f2bf(acc[i][j][r]);
      }
    }
  }
}

// ---------------- Clenshaw steps ----------------
// b_k = Y_k + 2*L*b_{k+1} - b_{k+2}   (all N x 288 bf16 panels; fp32 accumulate)
// In-place: D may equal P (same element read-then-written by its own thread).
// Block: 576 threads = 16 nodes x 36 lanes, 16B (8 bf16) per lane.

struct StepArgs {
  const unsigned short* H[4]; // gather source  b_{k+1}
  const unsigned short* Y[4]; // additive Y_k
  const unsigned short* P[4]; // b_{k+2} (may be null)
  unsigned short* D[4];       // dest b_k
};

__global__ __launch_bounds__(576) void cl_step_kernel(
    StepArgs a, const int* __restrict__ rowptr, const int* __restrict__ srcarr,
    const float* __restrict__ wn) {
  const int slot = blockIdx.y;
  const unsigned short* __restrict__ H = a.H[slot];
  const int t = threadIdx.x;
  const int ln = t % 36;
  const int node = blockIdx.x * 16 + t / 36;
  if (node >= NN) return;
  const int off = ln * 8;
  const int rs = rowptr[node];
  const int re = rowptr[node + 1];
  float acc[8];
#pragma unroll
  for (int q = 0; q < 8; q++) acc[q] = 0.f;
  for (int p = rs; p < re; ++p) {
    int r = srcarr[p];
    float w = wn[p];
    ushort8v h = *(const ushort8v*)(H + (size_t)r * FOUT + off);
#pragma unroll
    for (int q = 0; q < 8; q++) acc[q] += w * bf2f(h[q]);
  }
  size_t o = (size_t)node * FOUT + off;
  ushort8v y = *(const ushort8v*)(a.Y[slot] + o);
  ushort8v d;
  if (a.P[slot]) {
    ushort8v pp = *(const ushort8v*)(a.P[slot] + o);
#pragma unroll
    for (int q = 0; q < 8; q++) d[q] = f2bf(bf2f(y[q]) + 2.f * acc[q] - bf2f(pp[q]));
  } else {
#pragma unroll
    for (int q = 0; q < 8; q++) d[q] = f2bf(bf2f(y[q]) + 2.f * acc[q]);
  }
  *(ushort8v*)(a.D[slot] + o) = d;
}

// final: out[:, c*288 + f] = bias[f] + Y_0 + L*b_1 - b_2   (fp32 out)
struct FinalArgs {
  const unsigned short* H[4]; // b_1
  const unsigned short* Y[4]; // Y_0
  const unsigned short* P[4]; // b_2
  const float* B[4];          // bias
  int conv[4];
};

__global__ __launch_bounds__(576) void cl_final_kernel(
    FinalArgs a, const int* __restrict__ rowptr, const int* __restrict__ srcarr,
    const float* __restrict__ wn, float* __restrict__ out) {
  const int slot = blockIdx.y;
  const unsigned short* __restrict__ H = a.H[slot];
  const int t = threadIdx.x;
  const int ln = t % 36;
  const int node = blockIdx.x * 16 + t / 36;
  if (node >= NN) return;
  const int off = ln * 8;
  const int rs = rowptr[node];
  const int re = rowptr[node + 1];
  float acc[8];
#pragma unroll
  for (int q = 0; q < 8; q++) acc[q] = 0.f;
  for (int p = rs; p < re; ++p) {
    int r = srcarr[p];
    float w = wn[p];
    ushort8v h = *(const ushort8v*)(H + (size_t)r * FOUT + off);
#pragma unroll
    for (int q = 0; q < 8; q++) acc[q] += w * bf2f(h[q]);
  }
  size_t o = (size_t)node * FOUT + off;
  ushort8v y = *(const ushort8v*)(a.Y[slot] + o);
  ushort8v pp = *(const ushort8v*)(a.P[slot] + o);
  const float* bias = a.B[slot] + off;
  float r8[8];
#pragma unroll
  for (int q = 0; q < 8; q++)
    r8[q] = bias[q] + bf2f(y[q]) + acc[q] - bf2f(pp[q]);
  float* op = out + (size_t)node * FOUT_TOTAL + a.conv[slot] * FOUT + off;
  *(float4*)(op + 0) = make_float4(r8[0], r8[1], r8[2], r8[3]);
  *(float4*)(op + 4) = make_float4(r8[4], r8[5], r8[6], r8[7]);
}

// ---------------- launch ----------------

extern "C" void kernel_launch(void* const* d_in, const int* in_sizes, int n_in,
                              void* d_out, int out_size, void* d_ws, size_t ws_size,
                              hipStream_t stream) {
  const float* x = (const float*)d_in[0];
  const int* ei = (const int*)d_in[1];
  const float* W[4] = {(const float*)d_in[2], (const float*)d_in[4],
                       (const float*)d_in[6], (const float*)d_in[8]};
  const float* b[4] = {(const float*)d_in[3], (const float*)d_in[5],
                       (const float*)d_in[7], (const float*)d_in[9]};
  float* out = (float*)d_out;

  char* ws = (char*)d_ws;
  size_t off = 0;
  auto alloc = [&](size_t bytes) -> char* {
    char* p = ws + off;
    off += (bytes + 255) & ~(size_t)255;
    return p;
  };
  int* deg = (int*)alloc(NN * 4);
  int* indeg = (int*)alloc(NN * 4);
  int* rowptr = (int*)alloc((NN + 1) * 4);
  int* cursor = (int*)alloc(NN * 4);
  int* srcarr = (int*)alloc(NE * 4);
  float* wn = (float*)alloc(NE * 4);
  float* dinv = (float*)alloc(NN * 4);
  unsigned short* xb = (unsigned short*)alloc((size_t)NN * FIN * 2);       // bf16 x; reused as 4 spare panels
  unsigned short* Wt = (unsigned short*)alloc((size_t)NSLICE * WSL * 2);   // bf16 W^T
  unsigned short* Yall = (unsigned short*)alloc((size_t)NSLICE * NF * 2);  // bf16 Y panels

  hipMemsetAsync(deg, 0, NN * 4, stream);
  hipMemsetAsync(indeg, 0, NN * 4, stream);

  deg_kernel<<<(NE + 255) / 256, 256, 0, stream>>>(ei, deg, indeg);
  dinv_kernel<<<(NN + 255) / 256, 256, 0, stream>>>(deg, dinv);
  scan_kernel<<<1, 256, 0, stream>>>(indeg, rowptr, cursor);
  scatter_kernel<<<(NE + 255) / 256, 256, 0, stream>>>(ei, dinv, cursor, srcarr, wn);
  wtrans_kernel<<<(NSLICE * WSL + 255) / 256, 256, 0, stream>>>(W[0], W[1], W[2], W[3], Wt);
  xcast_kernel<<<(NN * FIN / 4 + 255) / 256, 256, 0, stream>>>(x, xb);

  // all 22 GEMMs in one dispatch; x = (slice,ntile) fastest for A-tile L2 reuse
  {
    dim3 grid(3 * NSLICE, (NN + 127) / 128);
    gemm_mfma_kernel<<<grid, 256, 0, stream>>>(xb, Wt, Yall);
  }

  // ---- Clenshaw schedule (host-side bookkeeping) ----
  const int nK[4] = {4, 5, 6, 7};
  const int st[4] = {0, 4, 9, 15};
  unsigned short* S[4]; // spare panels alias xb (xb no longer needed after GEMM)
  for (int c = 0; c < 4; c++) S[c] = xb + (size_t)c * NF;

  StepArgs sched[5];
  int nact[5] = {0, 0, 0, 0, 0};
  FinalArgs fa;

  for (int c = 3; c >= 0; c--) {
    int n = nK[c] - 1;        // Clenshaw degree (props per conv)
    int s0 = 6 - n;           // first global step for this conv
    unsigned short* Yn = Yall + (size_t)(st[c] + n) * NF; // holds b_n = Y_n initially
    unsigned short* A = S[c];
    for (int p = 1; p <= n; p++) {
      int s = s0 + p - 1;
      if (p < n) {
        unsigned short* H = (p & 1) ? Yn : A;
        unsigned short* D = (p & 1) ? A : Yn;
        int j = nact[s]++;
        sched[s].H[j] = H;
        sched[s].Y[j] = Yall + (size_t)(st[c] + n - p) * NF;
        sched[s].P[j] = (p == 1) ? nullptr : D; // in-place over b_{k+2}
        sched[s].D[j] = D;
      } else { // final at s == 5
        int j = 3 - c;
        fa.H[j] = ((n - 1) & 1) ? A : Yn; // loc(b_1)
        fa.P[j] = ((n - 2) & 1) ? A : Yn; // loc(b_2)
        fa.Y[j] = Yall + (size_t)st[c] * NF;
        fa.B[j] = b[c];
        fa.conv[j] = c;
      }
    }
  }

  for (int s = 0; s < 5; s++) {
    cl_step_kernel<<<dim3(NN / 16, nact[s]), 576, 0, stream>>>(sched[s], rowptr, srcarr, wn);
  }
  cl_final_kernel<<<dim3(NN / 16, 4), 576, 0, stream>>>(fa, rowptr, srcarr, wn, out);
}